// Round 8
// baseline (160.158 us; speedup 1.0000x reference)
//
#include <hip/hip_runtime.h>

// LocallyConnected2d: out[b,o,y,x] = sum_{c,i,j} x[b,c,y+i,x+j] * w[o,c,y,x,i*3+j]
// B=16, C_IN=16, H=W=64, C_OUT=16, KH=KW=3, OH=OW=62.
//
// Round 8: barrier-free, LDS-free. Four rounds at ~30us kernel showed the
// per-c __syncthreads serializes exposed L2/L3 latency (pipe sum says ~6us).
// Here each wave loads w directly (og wave-uniform -> one ~10-line region per
// f4 instr; co-og waves hit L1), x via float4, and the fully-unrolled c-loop
// runs an explicit 2-stage register pipeline: load c+1 regs, compute c.
// No __syncthreads anywhere -> compiler emits fine-grained vmcnt(N) and keeps
// ~24 loads in flight across each compute phase.
//  - lanes: xl = tid&15 (x position), us = (tid>>4)&3 (b-group);
//    wave v = tid>>6: og = v>>1 (UNIFORM in wave), b = ((v&1)*4+us)*2 + bi.
//  - tile 4o x 2b per thread; ~130 VGPR; __launch_bounds__(256,2) -> cap 256
//    (the only spill-free cap observed: (.,4)->64 and bare->128 both spilled).
//  - grid 62 x 4(xq) x 2(oh) = 496 blocks -> 2 blocks/CU, plain stores.

#define CIN   16
#define COUT  16
#define HH    64
#define WW    64
#define OHH   62
#define OWW   62
#define HW    (HH * WW)

#define WOSTR (CIN * OHH * OWW * 9)   // 553536 floats: o stride in w
#define WCSTR (OHH * OWW * 9)         // 34596 floats: c stride in w

__global__ __launch_bounds__(256, 2)
void lc2d(const float* __restrict__ xg,
          const float* __restrict__ wg,
          float* __restrict__ outg)
{
    const int tid = threadIdx.x;
    const int y   = blockIdx.x;          // 0..61
    const int xq  = blockIdx.y;          // 0..3  (x quarter)
    const int oh  = blockIdx.z;          // 0..1  (o half)
    const int x0  = xq * 16;

    const int xl  = tid & 15;            // x within quarter
    const int us  = (tid >> 4) & 3;      // b-group within wave
    const int v   = tid >> 6;            // wave 0..3
    const int og  = v >> 1;              // wave-uniform o-group
    const int bb  = ((v & 1) * 4 + us) * 2;   // base b for this thread (2 b's)

    const int pos = x0 + xl;
    const bool valid = pos < OWW;
    const int xp  = valid ? pos : (OWW - 1);

    // w base for (o = oh*8+og*4, c=0, y, xp, k=0); +t*WOSTR +c*WCSTR
    const float* wbase = wg + (size_t)(oh * 8 + og * 4) * WOSTR
                            + (size_t)(y * OWW + xp) * 9;
    // x base for (b=bb, c=0, y, xp); +bi*CIN*HW +c*HW +i*WW
    const float* xbase = xg + (size_t)bb * CIN * HW + (size_t)y * WW + xp;

    // pipeline registers (parity-indexed, fully unrolled loop -> static)
    float wv[2][4][9];     // [par][t][k]
    float xv[2][2][12];    // [par][bi][i*4+j], j=3 unused (f4 load)

    // ---- prologue: load c = 0 ----
    #pragma unroll
    for (int t = 0; t < 4; ++t) {
        const float* p = wbase + (size_t)t * WOSTR;
        float4 A = *(const float4*)p;        // k0..3
        float4 Bv = *(const float4*)(p + 4); // k4..7
        float  c8 = p[8];
        wv[0][t][0] = A.x;  wv[0][t][1] = A.y;  wv[0][t][2] = A.z;  wv[0][t][3] = A.w;
        wv[0][t][4] = Bv.x; wv[0][t][5] = Bv.y; wv[0][t][6] = Bv.z; wv[0][t][7] = Bv.w;
        wv[0][t][8] = c8;
    }
    #pragma unroll
    for (int bi = 0; bi < 2; ++bi) {
        const float* p = xbase + (size_t)bi * CIN * HW;
        #pragma unroll
        for (int i = 0; i < 3; ++i) {
            float4 r = *(const float4*)(p + i * WW);
            xv[0][bi][i * 4 + 0] = r.x;
            xv[0][bi][i * 4 + 1] = r.y;
            xv[0][bi][i * 4 + 2] = r.z;
        }
    }

    float acc[4][2];
    #pragma unroll
    for (int t = 0; t < 4; ++t) { acc[t][0] = 0.f; acc[t][1] = 0.f; }

    #pragma unroll
    for (int c = 0; c < CIN; ++c) {
        const int cu = c & 1;
        const int nu = cu ^ 1;

        // ---- load c+1 into the other parity (stays in flight over compute) ----
        if (c + 1 < CIN) {
            #pragma unroll
            for (int bi = 0; bi < 2; ++bi) {
                const float* p = xbase + (size_t)bi * CIN * HW + (size_t)(c + 1) * HW;
                #pragma unroll
                for (int i = 0; i < 3; ++i) {
                    float4 r = *(const float4*)(p + i * WW);
                    xv[nu][bi][i * 4 + 0] = r.x;
                    xv[nu][bi][i * 4 + 1] = r.y;
                    xv[nu][bi][i * 4 + 2] = r.z;
                }
            }
            #pragma unroll
            for (int t = 0; t < 4; ++t) {
                const float* p = wbase + (size_t)t * WOSTR + (size_t)(c + 1) * WCSTR;
                float4 A = *(const float4*)p;
                float4 Bv = *(const float4*)(p + 4);
                float  c8 = p[8];
                wv[nu][t][0] = A.x;  wv[nu][t][1] = A.y;  wv[nu][t][2] = A.z;  wv[nu][t][3] = A.w;
                wv[nu][t][4] = Bv.x; wv[nu][t][5] = Bv.y; wv[nu][t][6] = Bv.z; wv[nu][t][7] = Bv.w;
                wv[nu][t][8] = c8;
            }
        }

        // ---- compute on current parity: 4 o x 2 b x 9 k ----
        #pragma unroll
        for (int t = 0; t < 4; ++t) {
            #pragma unroll
            for (int bi = 0; bi < 2; ++bi) {
                float s = acc[t][bi];
                #pragma unroll
                for (int k = 0; k < 9; ++k) {
                    const int xi = (k / 3) * 4 + (k % 3);
                    s = fmaf(wv[cu][t][k], xv[cu][bi][xi], s);
                }
                acc[t][bi] = s;
            }
        }
    }

    if (valid) {
        #pragma unroll
        for (int t = 0; t < 4; ++t) {
            const int o = oh * 8 + og * 4 + t;
            #pragma unroll
            for (int bi = 0; bi < 2; ++bi) {
                const int b = bb + bi;
                outg[((size_t)(b * COUT + o) * OHH + y) * OWW + pos] = acc[t][bi];
            }
        }
    }
}

extern "C" void kernel_launch(void* const* d_in, const int* in_sizes, int n_in,
                              void* d_out, int out_size, void* d_ws, size_t ws_size,
                              hipStream_t stream) {
    const float* x = (const float*)d_in[0];
    const float* w = (const float*)d_in[1];
    float* out = (float*)d_out;

    dim3 grid(OHH, 4, 2);   // y, x-quarter, o-half
    lc2d<<<grid, dim3(256), 0, stream>>>(x, w, out);
}